// Round 1
// baseline (567.104 us; speedup 1.0000x reference)
//
#include <hip/hip_runtime.h>
#include <math.h>

#define NG 4096
#define NN 262144
#define D 128
#define M1 64
#define NH 8
#define EPS 1e-6f

// ---------------------------------------------------------------------------
// K1: per-node  h = LN(leaky(feat@W1+b1));  att = exp(h@W2+b2)
//     store att[N,8], atomicAdd into s[NG,8].
// One thread owns one node: 64 fp32 accumulators in VGPRs; W1/W2/b/g/beta are
// wave-uniform -> scalar loads, so the inner loop is v_fmac with SGPR operand.
// ---------------------------------------------------------------------------
__global__ __launch_bounds__(256) void k1_att(
    const float* __restrict__ feat, const int* __restrict__ batch,
    const float* __restrict__ W1, const float* __restrict__ b1,
    const float* __restrict__ g1, const float* __restrict__ beta1,
    const float* __restrict__ W2, const float* __restrict__ b2,
    float* __restrict__ att, float* __restrict__ s) {
  int n = blockIdx.x * 256 + threadIdx.x;  // grid exactly covers NN
  float acc[M1];
#pragma unroll
  for (int j = 0; j < M1; ++j) acc[j] = 0.f;

  const float* fr = feat + (size_t)n * D;
  for (int k = 0; k < D; k += 4) {
    float4 f4 = *(const float4*)(fr + k);
#pragma unroll
    for (int kk = 0; kk < 4; ++kk) {
      float fk = (&f4.x)[kk];
      const float* wrow = W1 + (k + kk) * M1;
#pragma unroll
      for (int j = 0; j < M1; ++j) acc[j] = fmaf(fk, wrow[j], acc[j]);
    }
  }

  // bias + leaky relu + in-thread LayerNorm over the 64 features
  float mu = 0.f;
#pragma unroll
  for (int j = 0; j < M1; ++j) {
    float v = acc[j] + b1[j];
    v = v > 0.f ? v : 0.01f * v;
    acc[j] = v;
    mu += v;
  }
  mu *= (1.f / M1);
  float var = 0.f;
#pragma unroll
  for (int j = 0; j < M1; ++j) {
    float dv = acc[j] - mu;
    var = fmaf(dv, dv, var);
  }
  var *= (1.f / M1);
  float inv = rsqrtf(var + EPS);
#pragma unroll
  for (int j = 0; j < M1; ++j)
    acc[j] = (acc[j] - mu) * inv * g1[j] + beta1[j];

  int g = batch[n];
  float av[NH];
#pragma unroll
  for (int h = 0; h < NH; ++h) {
    float a = b2[h];
#pragma unroll
    for (int j = 0; j < M1; ++j) a = fmaf(acc[j], W2[j * NH + h], a);
    av[h] = expf(a);
  }
  float4* ap = (float4*)(att + (size_t)n * NH);
  ap[0] = make_float4(av[0], av[1], av[2], av[3]);
  ap[1] = make_float4(av[4], av[5], av[6], av[7]);
#pragma unroll
  for (int h = 0; h < NH; ++h) atomicAdd(s + g * NH + h, av[h]);
}

// ---------------------------------------------------------------------------
// K2: block-per-graph.  out_row[8,128] = (sum_n att[n]⊗feat[n]) / s[g]
//     then o = LN(leaky(out_row@W3+b3)); o = LN(leaky(o@W4+b4)) -> d_out.
// Division by s moved AFTER the segment sum (algebraically identical).
// ---------------------------------------------------------------------------
__device__ inline int lbound(const int* __restrict__ a, int n, int v) {
  int lo = 0, hi = n;
  while (lo < hi) {
    int mid = (lo + hi) >> 1;
    if (a[mid] < v) lo = mid + 1; else hi = mid;
  }
  return lo;
}

__global__ __launch_bounds__(256) void k2_agg_mlp(
    const float* __restrict__ feat, const int* __restrict__ batch,
    const float* __restrict__ att, const float* __restrict__ s,
    const float* __restrict__ W3, const float* __restrict__ b3,
    const float* __restrict__ g3, const float* __restrict__ beta3,
    const float* __restrict__ W4, const float* __restrict__ b4,
    const float* __restrict__ g4, const float* __restrict__ beta4,
    float* __restrict__ out) {
  __shared__ float row[NH * D];   // aggregated graph row, [h*128+d]
  __shared__ float part[2][D];
  __shared__ float vec[D];
  __shared__ float sred[8];
  __shared__ float sred2[8];

  int gidx = blockIdx.x;
  int t = threadIdx.x;
  int lo = lbound(batch, NN, gidx);
  int hi = lbound(batch, NN, gidx + 1);

  int d = t & (D - 1);
  int hb = (t >> 7) * 4;  // waves 0,1 own heads 0..3; waves 2,3 own heads 4..7
  float a0 = 0.f, a1 = 0.f, a2 = 0.f, a3 = 0.f;
  for (int n = lo; n < hi; ++n) {
    float f = feat[(size_t)n * D + d];
    const float* ap = att + (size_t)n * NH + hb;  // wave-uniform -> s_load
    a0 = fmaf(ap[0], f, a0);
    a1 = fmaf(ap[1], f, a1);
    a2 = fmaf(ap[2], f, a2);
    a3 = fmaf(ap[3], f, a3);
  }
  if (hi > lo) {
    a0 /= s[gidx * NH + hb + 0];
    a1 /= s[gidx * NH + hb + 1];
    a2 /= s[gidx * NH + hb + 2];
    a3 /= s[gidx * NH + hb + 3];
  }
  row[(hb + 0) * D + d] = a0;
  row[(hb + 1) * D + d] = a1;
  row[(hb + 2) * D + d] = a2;
  row[(hb + 3) * D + d] = a3;
  __syncthreads();

  // ---- MLP1: [1024] @ W3[1024,128]; each output split across two threads
  int j = d;
  int half = t >> 7;
  {
    float p = 0.f;
    const float* w3 = W3 + j;
    int k0 = half * 512;
    for (int k = k0; k < k0 + 512; ++k)
      p = fmaf(row[k], w3[(size_t)k * D], p);
    part[half][j] = p;
  }
  __syncthreads();

  float v = 0.f;
  if (t < D) {
    v = part[0][t] + part[1][t] + b3[t];
    v = v > 0.f ? v : 0.01f * v;
  }
  // block LN over the 128 values held by threads 0..127
  {
    float xs = (t < D) ? v : 0.f;
    float xq = (t < D) ? v * v : 0.f;
#pragma unroll
    for (int off = 32; off > 0; off >>= 1) {
      xs += __shfl_down(xs, off);
      xq += __shfl_down(xq, off);
    }
    int lane = t & 63, wid = t >> 6;
    if (lane == 0) { sred[wid] = xs; sred[4 + wid] = xq; }
  }
  __syncthreads();
  {
    float sum = sred[0] + sred[1] + sred[2] + sred[3];
    float sq = sred[4] + sred[5] + sred[6] + sred[7];
    float mu = sum * (1.f / D);
    float var = sq * (1.f / D) - mu * mu;
    float inv = rsqrtf(var + EPS);
    if (t < D) vec[t] = (v - mu) * inv * g3[t] + beta3[t];
  }
  __syncthreads();

  // ---- MLP2: [128] @ W4[128,128]
  {
    float p2 = 0.f;
    int k0 = half * 64;
    const float* w4 = W4 + j;
    for (int k = k0; k < k0 + 64; ++k)
      p2 = fmaf(vec[k], w4[(size_t)k * D], p2);
    part[half][j] = p2;
  }
  __syncthreads();

  float w = 0.f;
  if (t < D) {
    w = part[0][t] + part[1][t] + b4[t];
    w = w > 0.f ? w : 0.01f * w;
  }
  {
    float xs = (t < D) ? w : 0.f;
    float xq = (t < D) ? w * w : 0.f;
#pragma unroll
    for (int off = 32; off > 0; off >>= 1) {
      xs += __shfl_down(xs, off);
      xq += __shfl_down(xq, off);
    }
    int lane = t & 63, wid = t >> 6;
    if (lane == 0) { sred2[wid] = xs; sred2[4 + wid] = xq; }
  }
  __syncthreads();
  {
    float sum = sred2[0] + sred2[1] + sred2[2] + sred2[3];
    float sq = sred2[4] + sred2[5] + sred2[6] + sred2[7];
    float mu = sum * (1.f / D);
    float var = sq * (1.f / D) - mu * mu;
    float inv = rsqrtf(var + EPS);
    if (t < D) out[(size_t)gidx * D + t] = (w - mu) * inv * g4[t] + beta4[t];
  }
}

extern "C" void kernel_launch(void* const* d_in, const int* in_sizes, int n_in,
                              void* d_out, int out_size, void* d_ws, size_t ws_size,
                              hipStream_t stream) {
  (void)in_sizes; (void)n_in; (void)out_size; (void)ws_size;
  const float* feat  = (const float*)d_in[0];
  const int*   batch = (const int*)d_in[1];
  const float* W1    = (const float*)d_in[2];
  const float* b1    = (const float*)d_in[3];
  const float* g1    = (const float*)d_in[4];
  const float* beta1 = (const float*)d_in[5];
  const float* W2    = (const float*)d_in[6];
  const float* b2    = (const float*)d_in[7];
  const float* W3    = (const float*)d_in[8];
  const float* b3    = (const float*)d_in[9];
  const float* g3    = (const float*)d_in[10];
  const float* beta3 = (const float*)d_in[11];
  const float* W4    = (const float*)d_in[12];
  const float* b4    = (const float*)d_in[13];
  const float* g4    = (const float*)d_in[14];
  const float* beta4 = (const float*)d_in[15];
  float* out = (float*)d_out;

  float* att = (float*)d_ws;                                     // NN*8 floats
  float* s   = (float*)((char*)d_ws + (size_t)NN * NH * 4);      // NG*8 floats

  hipMemsetAsync(s, 0, (size_t)NG * NH * 4, stream);
  k1_att<<<NN / 256, 256, 0, stream>>>(feat, batch, W1, b1, g1, beta1, W2, b2,
                                       att, s);
  k2_agg_mlp<<<NG, 256, 0, stream>>>(feat, batch, att, s, W3, b3, g3, beta3,
                                     W4, b4, g4, beta4, out);
}

// Round 2
// 416.216 us; speedup vs baseline: 1.3625x; 1.3625x over previous
//
#include <hip/hip_runtime.h>
#include <math.h>

#define NG 4096
#define NN 262144
#define D 128
#define M1 64
#define NH 8
#define EPS 1e-6f

__device__ inline float leaky(float x) { return x > 0.f ? x : 0.01f * x; }

// ---------------------------------------------------------------------------
// K1: per-node  h = LN(leaky(feat@W1+b1));  att = exp(h@W2+b2) -> att[N,8]
// One thread per node. feat row is explicitly double-buffered in registers
// (32B chunks) so HBM latency hides behind the 512-FMA compute per chunk.
// W1/W2/b/g/beta are wave-uniform -> scalar loads from K$.
// No atomics: the softmax denominator s is computed in K2.
// ---------------------------------------------------------------------------
__global__ __launch_bounds__(256) void k1_att(
    const float* __restrict__ feat, const float* __restrict__ W1,
    const float* __restrict__ b1, const float* __restrict__ g1,
    const float* __restrict__ beta1, const float* __restrict__ W2,
    const float* __restrict__ b2, float* __restrict__ att) {
  int n = blockIdx.x * 256 + threadIdx.x;  // grid exactly covers NN
  float acc[M1];
#pragma unroll
  for (int j = 0; j < M1; ++j) acc[j] = 0.f;

  const float4* fr = (const float4*)(feat + (size_t)n * D);  // 32 float4
  float4 buf[2][2];
  buf[0][0] = fr[0];
  buf[0][1] = fr[1];
#pragma unroll 2
  for (int c = 0; c < 16; ++c) {           // 16 chunks of 8 floats
    int cc = c & 1, nc = cc ^ 1;
    if (c < 15) {                          // prefetch next chunk
      buf[nc][0] = fr[(c + 1) * 2];
      buf[nc][1] = fr[(c + 1) * 2 + 1];
    }
#pragma unroll
    for (int q = 0; q < 2; ++q) {
      float4 f4 = buf[cc][q];
      int kb = c * 8 + q * 4;
#pragma unroll
      for (int kk = 0; kk < 4; ++kk) {
        float fk = (&f4.x)[kk];
        const float* wrow = W1 + (kb + kk) * M1;  // uniform -> s_load
#pragma unroll
        for (int j = 0; j < M1; ++j) acc[j] = fmaf(fk, wrow[j], acc[j]);
      }
    }
  }

  // bias + leaky + in-thread LayerNorm over 64 features
  float mu = 0.f;
#pragma unroll
  for (int j = 0; j < M1; ++j) {
    float v = leaky(acc[j] + b1[j]);
    acc[j] = v;
    mu += v;
  }
  mu *= (1.f / M1);
  float var = 0.f;
#pragma unroll
  for (int j = 0; j < M1; ++j) {
    float dv = acc[j] - mu;
    var = fmaf(dv, dv, var);
  }
  var *= (1.f / M1);
  float inv = rsqrtf(var + EPS);
#pragma unroll
  for (int j = 0; j < M1; ++j)
    acc[j] = (acc[j] - mu) * inv * g1[j] + beta1[j];

  float av[NH];
#pragma unroll
  for (int h = 0; h < NH; ++h) {
    float a = b2[h];
#pragma unroll
    for (int j = 0; j < M1; ++j) a = fmaf(acc[j], W2[j * NH + h], a);
    av[h] = expf(a);
  }
  float4* ap = (float4*)(att + (size_t)n * NH);
  ap[0] = make_float4(av[0], av[1], av[2], av[3]);
  ap[1] = make_float4(av[4], av[5], av[6], av[7]);
}

// ---------------------------------------------------------------------------
// K2: block-per-graph aggregation.
//   out_row[g, h*128+d] = (sum_n att[n][h]*feat[n][d]) / (sum_n att[n][h])
// 8 node-subgroups x 32 d4-lanes; coalesced float4 feat reads; LDS tree
// reduce; s computed in-block (division moved after the segment sum).
// ---------------------------------------------------------------------------
__device__ inline int lbound(const int* __restrict__ a, int n, int v) {
  int lo = 0, hi = n;
  while (lo < hi) {
    int mid = (lo + hi) >> 1;
    if (a[mid] < v) lo = mid + 1; else hi = mid;
  }
  return lo;
}

__global__ __launch_bounds__(256) void k2_agg(
    const float* __restrict__ feat, const int* __restrict__ batch,
    const float* __restrict__ att, float* __restrict__ out_row) {
  __shared__ float4 red4[8][8][32];  // [sub][h][d4], 32 KB
  __shared__ float s_part[8][8];     // [sub][h]

  int g = blockIdx.x, t = threadIdx.x;
  int lo = lbound(batch, NN, g);
  int hi = lbound(batch, NN, g + 1);

  int d4 = t & 31, sub = t >> 5;
  float4 acc[NH];
#pragma unroll
  for (int h = 0; h < NH; ++h) acc[h] = make_float4(0.f, 0.f, 0.f, 0.f);
  float satt[NH];
#pragma unroll
  for (int h = 0; h < NH; ++h) satt[h] = 0.f;

  for (int n = lo + sub; n < hi; n += 8) {
    float4 f = ((const float4*)(feat + (size_t)n * D))[d4];
    const float4* ap = (const float4*)(att + (size_t)n * NH);
    float4 a0 = ap[0], a1 = ap[1];
    float ah[NH] = {a0.x, a0.y, a0.z, a0.w, a1.x, a1.y, a1.z, a1.w};
#pragma unroll
    for (int h = 0; h < NH; ++h) {
      acc[h].x = fmaf(ah[h], f.x, acc[h].x);
      acc[h].y = fmaf(ah[h], f.y, acc[h].y);
      acc[h].z = fmaf(ah[h], f.z, acc[h].z);
      acc[h].w = fmaf(ah[h], f.w, acc[h].w);
      satt[h] += ah[h];
    }
  }
#pragma unroll
  for (int h = 0; h < NH; ++h) red4[sub][h][d4] = acc[h];
  if (d4 == 0) {
#pragma unroll
    for (int h = 0; h < NH; ++h) s_part[sub][h] = satt[h];
  }
  __syncthreads();

  // phase 2: thread t -> h = t>>5, d4 = t&31
  int h = t >> 5, dd = t & 31;
  float4 v = make_float4(0.f, 0.f, 0.f, 0.f);
  float s = 0.f;
#pragma unroll
  for (int sb = 0; sb < 8; ++sb) {
    float4 r = red4[sb][h][dd];
    v.x += r.x; v.y += r.y; v.z += r.z; v.w += r.w;
    s += s_part[sb][h];
  }
  float inv = (hi > lo) ? 1.f / s : 0.f;
  v.x *= inv; v.y *= inv; v.z *= inv; v.w *= inv;
  ((float4*)(out_row + (size_t)g * (NH * D) + h * D))[dd] = v;
}

// ---------------------------------------------------------------------------
// K3: MLP head over 8 graphs per block (512 blocks).
//   o = LN(leaky(X@W3+b3)); o = LN(leaky(o@W4+b4))
// X[8,1024] staged in LDS (wave-uniform broadcast reads); W3 streamed once
// per block (L2). Register tile: 4 graphs x 2 cols. LN via 32-lane shuffles.
// ---------------------------------------------------------------------------
__global__ __launch_bounds__(256) void k3_mlp(
    const float* __restrict__ out_row, const float* __restrict__ W3,
    const float* __restrict__ b3, const float* __restrict__ g3,
    const float* __restrict__ beta3, const float* __restrict__ W4,
    const float* __restrict__ b4, const float* __restrict__ g4,
    const float* __restrict__ beta4, float* __restrict__ out) {
  __shared__ float X[8][1024];     // 32 KB
  __shared__ float p1[2][8][128];  // 8 KB
  __shared__ float h2[8][128];     // 4 KB
  __shared__ float o2[8][128];     // 4 KB

  int gb = blockIdx.x * 8;  // first graph of this block
  int t = threadIdx.x;

  // stage X coalesced: 2048 float4s / 256 threads
  {
    const float4* src = (const float4*)(out_row + (size_t)gb * (NH * D));
    float4* dst = (float4*)&X[0][0];
#pragma unroll
    for (int i = 0; i < 8; ++i) dst[t + 256 * i] = src[t + 256 * i];
  }
  __syncthreads();

  // GEMM1: [8,1024]@[1024,128]; thread tile 4 graphs x 2 cols, k split in 2
  int j2 = (t & 63) * 2, gq = ((t >> 6) & 1) * 4, half = t >> 7;
  float a[4][2];
#pragma unroll
  for (int i = 0; i < 4; ++i) { a[i][0] = 0.f; a[i][1] = 0.f; }
  int k0 = half * 512;
  for (int k = k0; k < k0 + 512; k += 4) {
    float4 xv[4];
#pragma unroll
    for (int i = 0; i < 4; ++i) xv[i] = *(const float4*)&X[gq + i][k];
#pragma unroll
    for (int kk = 0; kk < 4; ++kk) {
      float2 w = *(const float2*)(W3 + (size_t)(k + kk) * D + j2);
#pragma unroll
      for (int i = 0; i < 4; ++i) {
        float x = (&xv[i].x)[kk];
        a[i][0] = fmaf(x, w.x, a[i][0]);
        a[i][1] = fmaf(x, w.y, a[i][1]);
      }
    }
  }
#pragma unroll
  for (int i = 0; i < 4; ++i)
    *(float2*)&p1[half][gq + i][j2] = make_float2(a[i][0], a[i][1]);
  __syncthreads();

  // leaky + LN1: 32 threads per graph, 4 cols each
  int g = t >> 5, c0 = (t & 31) * 4;
  {
    float v[4], sum = 0.f, sq = 0.f;
#pragma unroll
    for (int i = 0; i < 4; ++i) {
      float x = leaky(p1[0][g][c0 + i] + p1[1][g][c0 + i] + b3[c0 + i]);
      v[i] = x;
      sum += x;
      sq = fmaf(x, x, sq);
    }
#pragma unroll
    for (int off = 16; off > 0; off >>= 1) {
      sum += __shfl_xor(sum, off);
      sq += __shfl_xor(sq, off);
    }
    float mu = sum * (1.f / D);
    float var = sq * (1.f / D) - mu * mu;
    float inv = rsqrtf(var + EPS);
#pragma unroll
    for (int i = 0; i < 4; ++i)
      h2[g][c0 + i] = (v[i] - mu) * inv * g3[c0 + i] + beta3[c0 + i];
  }
  __syncthreads();

  // MLP2: [8,128]@[128,128]; thread tile 4 graphs x 1 col
  {
    int j = t & 127, gh = (t >> 7) * 4;
    float a2[4] = {0.f, 0.f, 0.f, 0.f};
    for (int k = 0; k < 128; k += 4) {
      float4 hv[4];
#pragma unroll
      for (int i = 0; i < 4; ++i) hv[i] = *(const float4*)&h2[gh + i][k];
#pragma unroll
      for (int kk = 0; kk < 4; ++kk) {
        float w = W4[(size_t)(k + kk) * D + j];
#pragma unroll
        for (int i = 0; i < 4; ++i) a2[i] = fmaf((&hv[i].x)[kk], w, a2[i]);
      }
    }
#pragma unroll
    for (int i = 0; i < 4; ++i) o2[gh + i][j] = a2[i];
  }
  __syncthreads();

  // leaky + LN2 + store
  {
    float v[4], sum = 0.f, sq = 0.f;
#pragma unroll
    for (int i = 0; i < 4; ++i) {
      float x = leaky(o2[g][c0 + i] + b4[c0 + i]);
      v[i] = x;
      sum += x;
      sq = fmaf(x, x, sq);
    }
#pragma unroll
    for (int off = 16; off > 0; off >>= 1) {
      sum += __shfl_xor(sum, off);
      sq += __shfl_xor(sq, off);
    }
    float mu = sum * (1.f / D);
    float var = sq * (1.f / D) - mu * mu;
    float inv = rsqrtf(var + EPS);
    float4 res;
#pragma unroll
    for (int i = 0; i < 4; ++i)
      (&res.x)[i] = (v[i] - mu) * inv * g4[c0 + i] + beta4[c0 + i];
    *(float4*)(out + (size_t)(gb + g) * D + c0) = res;
  }
}

extern "C" void kernel_launch(void* const* d_in, const int* in_sizes, int n_in,
                              void* d_out, int out_size, void* d_ws, size_t ws_size,
                              hipStream_t stream) {
  (void)in_sizes; (void)n_in; (void)out_size; (void)ws_size;
  const float* feat  = (const float*)d_in[0];
  const int*   batch = (const int*)d_in[1];
  const float* W1    = (const float*)d_in[2];
  const float* b1    = (const float*)d_in[3];
  const float* g1    = (const float*)d_in[4];
  const float* beta1 = (const float*)d_in[5];
  const float* W2    = (const float*)d_in[6];
  const float* b2    = (const float*)d_in[7];
  const float* W3    = (const float*)d_in[8];
  const float* b3    = (const float*)d_in[9];
  const float* g3    = (const float*)d_in[10];
  const float* beta3 = (const float*)d_in[11];
  const float* W4    = (const float*)d_in[12];
  const float* b4    = (const float*)d_in[13];
  const float* g4    = (const float*)d_in[14];
  const float* beta4 = (const float*)d_in[15];
  float* out = (float*)d_out;

  float* att     = (float*)d_ws;                                   // N*8 f32
  float* out_row = (float*)((char*)d_ws + (size_t)NN * NH * 4);    // NG*1024

  k1_att<<<NN / 256, 256, 0, stream>>>(feat, W1, b1, g1, beta1, W2, b2, att);
  k2_agg<<<NG, 256, 0, stream>>>(feat, batch, att, out_row);
  k3_mlp<<<NG / 8, 256, 0, stream>>>(out_row, W3, b3, g3, beta3, W4, b4, g4,
                                     beta4, out);
}

// Round 3
// 301.433 us; speedup vs baseline: 1.8814x; 1.3808x over previous
//
#include <hip/hip_runtime.h>
#include <math.h>

#define NG 4096
#define NN 262144
#define D 128
#define M1 64
#define NH 8
#define EPS 1e-6f

typedef __attribute__((ext_vector_type(8))) short short8;
typedef __attribute__((ext_vector_type(4))) float f32x4;

__device__ inline float leaky(float x) { return x > 0.f ? x : 0.01f * x; }

// fp32 -> bf16 round-to-nearest-even
__device__ inline short f2bf(float f) {
  union { float f; unsigned u; } v; v.f = f;
  unsigned r = (v.u + 0x7fffu + ((v.u >> 16) & 1u)) >> 16;
  return (short)r;
}

// ---------------------------------------------------------------------------
// K0: graph offsets via binary search, once (4097 threads, overlapped chases)
// ---------------------------------------------------------------------------
__global__ void k0_offs(const int* __restrict__ batch, int* __restrict__ offs) {
  int i = blockIdx.x * 256 + threadIdx.x;
  if (i <= NG) {
    int lo = 0, hi = NN;
    while (lo < hi) {
      int mid = (lo + hi) >> 1;
      if (batch[mid] < i) lo = mid + 1; else hi = mid;
    }
    offs[i] = lo;
  }
}

// ---------------------------------------------------------------------------
// K1 (MFMA bf16): h = LN64(leaky(feat@W1+b1)); att = exp(h@W2+b2)
// Block = 256 thr = 4 waves, 128 nodes (32/wave as 2 M-tiles).
// GEMM1: A = feat (global fp32 -> bf16 frags), B = W1T in LDS (b128 reads).
// LN on C-frags via 16-lane shfl_xor; h -> LDS bf16; GEMM2 vs W2T (N pad 16).
// Fragment layouts per m89/m120: A[m=l&15][k=(l>>4)*8+i], B[k=(l>>4)*8+i][n=l&15],
// C: col=l&15, row=(l>>4)*4+reg.
// ---------------------------------------------------------------------------
__global__ __launch_bounds__(256) void k1_att(
    const float* __restrict__ feat, const float* __restrict__ W1,
    const float* __restrict__ b1, const float* __restrict__ g1,
    const float* __restrict__ beta1, const float* __restrict__ W2,
    const float* __restrict__ b2, float* __restrict__ att) {
  __shared__ short W1T[M1][D + 8];    // [j][k] bf16, +8 pad: 2-way banks
  __shared__ short W2T[16][M1 + 8];   // [hh][j] bf16, rows 8..15 = 0
  __shared__ short hb[128][72];       // h bf16, stride 72 (144 B, 16B-aligned)

  int t = threadIdx.x;
  // stage W1T (transpose 128x64 -> [j][k])
#pragma unroll
  for (int i = 0; i < 8; ++i) {
    int idx4 = t + 256 * i;           // 2048 float4s of W1
    int k = idx4 >> 4;
    int j = (idx4 & 15) * 4;
    float4 wv = *(const float4*)(W1 + k * M1 + j);
    W1T[j + 0][k] = f2bf(wv.x);
    W1T[j + 1][k] = f2bf(wv.y);
    W1T[j + 2][k] = f2bf(wv.z);
    W1T[j + 3][k] = f2bf(wv.w);
  }
  // stage W2T (transpose 64x8 -> [hh][j], zero-pad hh 8..15)
#pragma unroll
  for (int i = 0; i < 4; ++i) {
    int e = t * 4 + i;
    int hh = e >> 6, j = e & 63;
    W2T[hh][j] = (hh < NH) ? f2bf(W2[j * NH + hh]) : (short)0;
  }
  __syncthreads();

  int w = t >> 6, l = t & 63;
  int lr = l & 15, lq = l >> 4;       // tile-row lane, quad
  int nb = blockIdx.x * 128 + w * 32; // this wave's 32 nodes

  // A fragments: feat rows, fp32 -> bf16. 16 loads issued up front.
  short8 afr[2][4];
#pragma unroll
  for (int mt = 0; mt < 2; ++mt) {
    const float* rp = feat + (size_t)(nb + mt * 16 + lr) * D + lq * 8;
#pragma unroll
    for (int c = 0; c < 4; ++c) {
      float4 x0 = *(const float4*)(rp + c * 32);
      float4 x1 = *(const float4*)(rp + c * 32 + 4);
      short8 a;
      a[0] = f2bf(x0.x); a[1] = f2bf(x0.y); a[2] = f2bf(x0.z); a[3] = f2bf(x0.w);
      a[4] = f2bf(x1.x); a[5] = f2bf(x1.y); a[6] = f2bf(x1.z); a[7] = f2bf(x1.w);
      afr[mt][c] = a;
    }
  }

  // GEMM1: [32 nodes x 64 j], K=128
  f32x4 acc[2][4];
#pragma unroll
  for (int mt = 0; mt < 2; ++mt)
#pragma unroll
    for (int nt = 0; nt < 4; ++nt) acc[mt][nt] = (f32x4){0.f, 0.f, 0.f, 0.f};
#pragma unroll
  for (int c = 0; c < 4; ++c) {
#pragma unroll
    for (int nt = 0; nt < 4; ++nt) {
      short8 bfr = *(const short8*)&W1T[nt * 16 + lr][c * 32 + lq * 8];
      acc[0][nt] = __builtin_amdgcn_mfma_f32_16x16x32_bf16(afr[0][c], bfr, acc[0][nt], 0, 0, 0);
      acc[1][nt] = __builtin_amdgcn_mfma_f32_16x16x32_bf16(afr[1][c], bfr, acc[1][nt], 0, 0, 0);
    }
  }

  // bias + leaky + LN over j (64) on C-frag layout; write h (bf16) to LDS
  float b1v[4], g1v[4], btv[4];
#pragma unroll
  for (int nt = 0; nt < 4; ++nt) {
    b1v[nt] = b1[nt * 16 + lr];
    g1v[nt] = g1[nt * 16 + lr];
    btv[nt] = beta1[nt * 16 + lr];
  }
#pragma unroll
  for (int mt = 0; mt < 2; ++mt) {
#pragma unroll
    for (int r = 0; r < 4; ++r) {
      float x[4], s1 = 0.f, s2 = 0.f;
#pragma unroll
      for (int nt = 0; nt < 4; ++nt) {
        float xv = leaky(acc[mt][nt][r] + b1v[nt]);
        x[nt] = xv;
        s1 += xv;
        s2 = fmaf(xv, xv, s2);
      }
#pragma unroll
      for (int off = 1; off < 16; off <<= 1) {  // reduce across 16 lr-lanes
        s1 += __shfl_xor(s1, off);
        s2 += __shfl_xor(s2, off);
      }
      float mu = s1 * (1.f / M1);
      float var = s2 * (1.f / M1) - mu * mu;
      float inv = rsqrtf(var + EPS);
      int node = w * 32 + mt * 16 + lq * 4 + r;
#pragma unroll
      for (int nt = 0; nt < 4; ++nt)
        hb[node][nt * 16 + lr] = f2bf((x[nt] - mu) * inv * g1v[nt] + btv[nt]);
    }
  }
  __syncthreads();

  // GEMM2: [32 nodes x 16(8) hh], K=64
  f32x4 acc2[2];
  acc2[0] = (f32x4){0.f, 0.f, 0.f, 0.f};
  acc2[1] = (f32x4){0.f, 0.f, 0.f, 0.f};
#pragma unroll
  for (int c2 = 0; c2 < 2; ++c2) {
    short8 bfr2 = *(const short8*)&W2T[lr][c2 * 32 + lq * 8];
#pragma unroll
    for (int mt = 0; mt < 2; ++mt) {
      short8 af2 = *(const short8*)&hb[w * 32 + mt * 16 + lr][c2 * 32 + lq * 8];
      acc2[mt] = __builtin_amdgcn_mfma_f32_16x16x32_bf16(af2, bfr2, acc2[mt], 0, 0, 0);
    }
  }
  if (lr < NH) {
    float b2v = b2[lr];
#pragma unroll
    for (int mt = 0; mt < 2; ++mt)
#pragma unroll
      for (int r = 0; r < 4; ++r) {
        int node = nb + mt * 16 + lq * 4 + r;
        att[(size_t)node * NH + lr] = expf(acc2[mt][r] + b2v);
      }
  }
}

// ---------------------------------------------------------------------------
// K2: block-per-graph aggregation, offsets precomputed, depth-1 prefetch,
// 20 KB LDS (8 blocks/CU). out_row[g][h*128+d] = (sum att*feat)/(sum att)
// ---------------------------------------------------------------------------
__global__ __launch_bounds__(256) void k2_agg(
    const float* __restrict__ feat, const int* __restrict__ offs,
    const float* __restrict__ att, float* __restrict__ out_row) {
  __shared__ float4 red[4][NH][32];   // 16 KB
  __shared__ float reds[4][NH][32];   // 4 KB

  int g = blockIdx.x, t = threadIdx.x;
  int d4 = t & 31, sub = t >> 5;
  int lo = offs[g], hi = offs[g + 1];

  float4 acc[NH];
  float sa[NH];
#pragma unroll
  for (int h = 0; h < NH; ++h) {
    acc[h] = make_float4(0.f, 0.f, 0.f, 0.f);
    sa[h] = 0.f;
  }

  const float4* fv = (const float4*)feat;
  const float4* av = (const float4*)att;
  int n = lo + sub;
  float4 fc, a0c, a1c;
  if (n < hi) {
    fc = fv[(size_t)n * 32 + d4];
    a0c = av[(size_t)n * 2];
    a1c = av[(size_t)n * 2 + 1];
  }
  while (n < hi) {
    int n2 = n + 8;
    float4 fn, a0n, a1n;
    if (n2 < hi) {  // prefetch next iteration before computing current
      fn = fv[(size_t)n2 * 32 + d4];
      a0n = av[(size_t)n2 * 2];
      a1n = av[(size_t)n2 * 2 + 1];
    }
    float ah[NH] = {a0c.x, a0c.y, a0c.z, a0c.w, a1c.x, a1c.y, a1c.z, a1c.w};
#pragma unroll
    for (int h = 0; h < NH; ++h) {
      acc[h].x = fmaf(ah[h], fc.x, acc[h].x);
      acc[h].y = fmaf(ah[h], fc.y, acc[h].y);
      acc[h].z = fmaf(ah[h], fc.z, acc[h].z);
      acc[h].w = fmaf(ah[h], fc.w, acc[h].w);
      sa[h] += ah[h];
    }
    fc = fn; a0c = a0n; a1c = a1n;
    n = n2;
  }

  // hierarchical cross-sub reduction (8 -> 4 -> 2 -> 1)
  if (sub >= 4) {
#pragma unroll
    for (int h = 0; h < NH; ++h) {
      red[sub - 4][h][d4] = acc[h];
      reds[sub - 4][h][d4] = sa[h];
    }
  }
  __syncthreads();
  if (sub < 4) {
#pragma unroll
    for (int h = 0; h < NH; ++h) {
      float4 r = red[sub][h][d4];
      acc[h].x += r.x; acc[h].y += r.y; acc[h].z += r.z; acc[h].w += r.w;
      sa[h] += reds[sub][h][d4];
    }
  }
  __syncthreads();
  if (sub >= 2 && sub < 4) {
#pragma unroll
    for (int h = 0; h < NH; ++h) {
      red[sub - 2][h][d4] = acc[h];
      reds[sub - 2][h][d4] = sa[h];
    }
  }
  __syncthreads();
  if (sub < 2) {
#pragma unroll
    for (int h = 0; h < NH; ++h) {
      float4 r = red[sub][h][d4];
      acc[h].x += r.x; acc[h].y += r.y; acc[h].z += r.z; acc[h].w += r.w;
      sa[h] += reds[sub][h][d4];
    }
  }
  __syncthreads();
  if (sub == 1) {
#pragma unroll
    for (int h = 0; h < NH; ++h) {
      red[0][h][d4] = acc[h];
      reds[0][h][d4] = sa[h];
    }
  }
  __syncthreads();
  if (sub == 0) {
    float4* orow = (float4*)(out_row + (size_t)g * (NH * D));
#pragma unroll
    for (int h = 0; h < NH; ++h) {
      float4 r = red[0][h][d4];
      float st = sa[h] + reds[0][h][d4];
      float inv = st > 0.f ? 1.f / st : 0.f;
      float4 v;
      v.x = (acc[h].x + r.x) * inv;
      v.y = (acc[h].y + r.y) * inv;
      v.z = (acc[h].z + r.z) * inv;
      v.w = (acc[h].w + r.w) * inv;
      orow[h * 32 + d4] = v;
    }
  }
}

// ---------------------------------------------------------------------------
// K3: MLP head over 8 graphs per block (unchanged from round 2 — attribution)
// ---------------------------------------------------------------------------
__global__ __launch_bounds__(256) void k3_mlp(
    const float* __restrict__ out_row, const float* __restrict__ W3,
    const float* __restrict__ b3, const float* __restrict__ g3,
    const float* __restrict__ beta3, const float* __restrict__ W4,
    const float* __restrict__ b4, const float* __restrict__ g4,
    const float* __restrict__ beta4, float* __restrict__ out) {
  __shared__ float X[8][1024];
  __shared__ float p1[2][8][128];
  __shared__ float h2[8][128];
  __shared__ float o2[8][128];

  int gb = blockIdx.x * 8;
  int t = threadIdx.x;

  {
    const float4* src = (const float4*)(out_row + (size_t)gb * (NH * D));
    float4* dst = (float4*)&X[0][0];
#pragma unroll
    for (int i = 0; i < 8; ++i) dst[t + 256 * i] = src[t + 256 * i];
  }
  __syncthreads();

  int j2 = (t & 63) * 2, gq = ((t >> 6) & 1) * 4, half = t >> 7;
  float a[4][2];
#pragma unroll
  for (int i = 0; i < 4; ++i) { a[i][0] = 0.f; a[i][1] = 0.f; }
  int k0 = half * 512;
  for (int k = k0; k < k0 + 512; k += 4) {
    float4 xv[4];
#pragma unroll
    for (int i = 0; i < 4; ++i) xv[i] = *(const float4*)&X[gq + i][k];
#pragma unroll
    for (int kk = 0; kk < 4; ++kk) {
      float2 wv = *(const float2*)(W3 + (size_t)(k + kk) * D + j2);
#pragma unroll
      for (int i = 0; i < 4; ++i) {
        float x = (&xv[i].x)[kk];
        a[i][0] = fmaf(x, wv.x, a[i][0]);
        a[i][1] = fmaf(x, wv.y, a[i][1]);
      }
    }
  }
#pragma unroll
  for (int i = 0; i < 4; ++i)
    *(float2*)&p1[half][gq + i][j2] = make_float2(a[i][0], a[i][1]);
  __syncthreads();

  int g = t >> 5, c0 = (t & 31) * 4;
  {
    float v[4], sum = 0.f, sq = 0.f;
#pragma unroll
    for (int i = 0; i < 4; ++i) {
      float x = leaky(p1[0][g][c0 + i] + p1[1][g][c0 + i] + b3[c0 + i]);
      v[i] = x;
      sum += x;
      sq = fmaf(x, x, sq);
    }
#pragma unroll
    for (int off = 16; off > 0; off >>= 1) {
      sum += __shfl_xor(sum, off);
      sq += __shfl_xor(sq, off);
    }
    float mu = sum * (1.f / D);
    float var = sq * (1.f / D) - mu * mu;
    float inv = rsqrtf(var + EPS);
#pragma unroll
    for (int i = 0; i < 4; ++i)
      h2[g][c0 + i] = (v[i] - mu) * inv * g3[c0 + i] + beta3[c0 + i];
  }
  __syncthreads();

  {
    int j = t & 127, gh = (t >> 7) * 4;
    float a2[4] = {0.f, 0.f, 0.f, 0.f};
    for (int k = 0; k < 128; k += 4) {
      float4 hv[4];
#pragma unroll
      for (int i = 0; i < 4; ++i) hv[i] = *(const float4*)&h2[gh + i][k];
#pragma unroll
      for (int kk = 0; kk < 4; ++kk) {
        float wv = W4[(size_t)(k + kk) * D + j];
#pragma unroll
        for (int i = 0; i < 4; ++i) a2[i] = fmaf((&hv[i].x)[kk], wv, a2[i]);
      }
    }
#pragma unroll
    for (int i = 0; i < 4; ++i) o2[gh + i][j] = a2[i];
  }
  __syncthreads();

  {
    float v[4], sum = 0.f, sq = 0.f;
#pragma unroll
    for (int i = 0; i < 4; ++i) {
      float x = leaky(o2[g][c0 + i] + b4[c0 + i]);
      v[i] = x;
      sum += x;
      sq = fmaf(x, x, sq);
    }
#pragma unroll
    for (int off = 16; off > 0; off >>= 1) {
      sum += __shfl_xor(sum, off);
      sq += __shfl_xor(sq, off);
    }
    float mu = sum * (1.f / D);
    float var = sq * (1.f / D) - mu * mu;
    float inv = rsqrtf(var + EPS);
    float4 res;
#pragma unroll
    for (int i = 0; i < 4; ++i)
      (&res.x)[i] = (v[i] - mu) * inv * g4[c0 + i] + beta4[c0 + i];
    *(float4*)(out + (size_t)(gb + g) * D + c0) = res;
  }
}

extern "C" void kernel_launch(void* const* d_in, const int* in_sizes, int n_in,
                              void* d_out, int out_size, void* d_ws, size_t ws_size,
                              hipStream_t stream) {
  (void)in_sizes; (void)n_in; (void)out_size; (void)ws_size;
  const float* feat  = (const float*)d_in[0];
  const int*   batch = (const int*)d_in[1];
  const float* W1    = (const float*)d_in[2];
  const float* b1    = (const float*)d_in[3];
  const float* g1    = (const float*)d_in[4];
  const float* beta1 = (const float*)d_in[5];
  const float* W2    = (const float*)d_in[6];
  const float* b2    = (const float*)d_in[7];
  const float* W3    = (const float*)d_in[8];
  const float* b3    = (const float*)d_in[9];
  const float* g3    = (const float*)d_in[10];
  const float* beta3 = (const float*)d_in[11];
  const float* W4    = (const float*)d_in[12];
  const float* b4    = (const float*)d_in[13];
  const float* g4    = (const float*)d_in[14];
  const float* beta4 = (const float*)d_in[15];
  float* out = (float*)d_out;

  char* ws = (char*)d_ws;
  float* att     = (float*)ws;                                   // N*8 f32
  float* out_row = (float*)(ws + (size_t)NN * NH * 4);           // NG*1024 f32
  int*   offs    = (int*)(ws + (size_t)NN * NH * 4 + (size_t)NG * NH * D * 4);

  k0_offs<<<(NG + 256) / 256, 256, 0, stream>>>(batch, offs);
  k1_att<<<NN / 128, 256, 0, stream>>>(feat, W1, b1, g1, beta1, W2, b2, att);
  k2_agg<<<NG, 256, 0, stream>>>(feat, offs, att, out_row);
  k3_mlp<<<NG / 8, 256, 0, stream>>>(out_row, W3, b3, g3, beta3, W4, b4, g4,
                                     beta4, out);
}